// Round 10
// baseline (6037.133 us; speedup 1.0000x reference)
//
#include <hip/hip_runtime.h>
#include <math.h>

#define B_ 64
#define T_ 2048
#define D_ 512
#define BT_ (B_ * T_)   // 131072
#define XWORDS (B_ * D_)   // 32768 8-byte words per parity slot: [batch][512]

typedef unsigned long long u64;

// ---------------------------------------------------------------------------
// Kernel 1: weight prep (transpose to k-major for coalesced GEMM/GEMV reads)
// ---------------------------------------------------------------------------
__global__ void prep_weights(const float* __restrict__ tau_w,
                             const float* __restrict__ mem_w,
                             float* __restrict__ Wcat,
                             float* __restrict__ WTh) {
    int idx = blockIdx.x * 256 + threadIdx.x;   // 0 .. 524287
    {
        int k = idx >> 10, j = idx & 1023;
        float v = (j < 512) ? tau_w[j * 1024 + k] : mem_w[(j - 512) * 512 + k];
        Wcat[idx] = v;
    }
    if (idx < 512 * 512) {
        int k = idx >> 9, d = idx & 511;
        WTh[idx] = tau_w[d * 1024 + 512 + k];
    }
}

// ---------------------------------------------------------------------------
// Kernel 2: f32 GEMM  C[131072][1024] = X[131072][512] @ Wcat[512][1024] + bias
// ---------------------------------------------------------------------------
__global__ __launch_bounds__(256, 2)
void gemm_xw(const float* __restrict__ X, const float* __restrict__ Wc,
             const float* __restrict__ tau_b, const float* __restrict__ mem_b,
             float* __restrict__ Aout, float* __restrict__ Mout) {
    __shared__ __align__(16) float As[16][128];  // [k][m]
    __shared__ __align__(16) float Bs[16][128];  // [k][n]
    const int bn = blockIdx.x;          // 0..7
    const int bm = blockIdx.y;          // 0..1023
    const int tid = threadIdx.x;
    const int tm = (tid >> 4) << 3;
    const int tn = (tid & 15) << 3;
    const int m0 = bm * 128, n0 = bn * 128;

    const float4* X4 = (const float4*)X;
    const float4* Wc4 = (const float4*)Wc;

    float acc[8][8];
#pragma unroll
    for (int i = 0; i < 8; i++)
#pragma unroll
        for (int j = 0; j < 8; j++) acc[i][j] = 0.0f;

    const int ar = tid >> 1;              // 0..127 row in tile
    const int ac2 = (tid & 1) * 2;        // float4 col 0 or 2
    const int bkr = tid >> 4;             // 0..15
    const int bc = (tid & 15) * 2;        // float4 col 0..30

    for (int kt = 0; kt < 512; kt += 16) {
        float4 av0 = X4[(m0 + ar) * 128 + (kt >> 2) + ac2];
        float4 av1 = X4[(m0 + ar) * 128 + (kt >> 2) + ac2 + 1];
        float4 bv0 = Wc4[(kt + bkr) * 256 + bn * 32 + bc];
        float4 bv1 = Wc4[(kt + bkr) * 256 + bn * 32 + bc + 1];
        __syncthreads();   // protect previous iteration's reads
        As[ac2 * 4 + 0][ar] = av0.x;
        As[ac2 * 4 + 1][ar] = av0.y;
        As[ac2 * 4 + 2][ar] = av0.z;
        As[ac2 * 4 + 3][ar] = av0.w;
        As[ac2 * 4 + 4][ar] = av1.x;
        As[ac2 * 4 + 5][ar] = av1.y;
        As[ac2 * 4 + 6][ar] = av1.z;
        As[ac2 * 4 + 7][ar] = av1.w;
        *(float4*)&Bs[bkr][bc * 4] = bv0;
        *(float4*)&Bs[bkr][bc * 4 + 4] = bv1;
        __syncthreads();
#pragma unroll
        for (int kk = 0; kk < 16; kk++) {
            float4 a0 = *(const float4*)&As[kk][tm];
            float4 a1 = *(const float4*)&As[kk][tm + 4];
            float4 b0 = *(const float4*)&Bs[kk][tn];
            float4 b1 = *(const float4*)&Bs[kk][tn + 4];
            float av[8] = {a0.x, a0.y, a0.z, a0.w, a1.x, a1.y, a1.z, a1.w};
            float bv[8] = {b0.x, b0.y, b0.z, b0.w, b1.x, b1.y, b1.z, b1.w};
#pragma unroll
            for (int i = 0; i < 8; i++)
#pragma unroll
                for (int j = 0; j < 8; j++)
                    acc[i][j] = fmaf(av[i], bv[j], acc[i][j]);
        }
    }

    const bool isA = (bn < 4);
    float* Cout = isA ? Aout : Mout;
    const float* bias = isA ? tau_b : mem_b;
    const int ncol0 = (isA ? n0 : n0 - 512) + tn;
    float bj[8];
#pragma unroll
    for (int j = 0; j < 8; j++) bj[j] = bias[ncol0 + j];
#pragma unroll
    for (int i = 0; i < 8; i++) {
        size_t off = (size_t)(m0 + tm + i) * 512 + ncol0;
        float4 o0, o1;
        o0.x = acc[i][0] + bj[0]; o0.y = acc[i][1] + bj[1];
        o0.z = acc[i][2] + bj[2]; o0.w = acc[i][3] + bj[3];
        o1.x = acc[i][4] + bj[4]; o1.y = acc[i][5] + bj[5];
        o1.z = acc[i][6] + bj[6]; o1.w = acc[i][7] + bj[7];
        *(float4*)&Cout[off] = o0;
        *(float4*)&Cout[off + 4] = o1;
    }
}

// ---------------------------------------------------------------------------
// Kernel 3: reset sync state every launch (graph-replay safe).
// Slot0 words = {seq=0, tau=1.0} (the t=0 carry); slot1 words = {seq=0, *}.
// ---------------------------------------------------------------------------
__global__ void init_sync(u64* __restrict__ xchg, int* __restrict__ ctr) {
    int idx = blockIdx.x * 256 + threadIdx.x;   // 0 .. 65535
    if (idx < 2 * XWORDS) xchg[idx] = (idx < XWORDS) ? 0x3F800000ull : 0ull;
    if (idx < 16) ctr[idx] = 0;
}

// ---------------------------------------------------------------------------
// Kernel 4: cooperative scan — LDS weights + readlane tau + 1-barrier step.
//
// r8 proved LDS weights work (4.1ms); r9 proved readlane works but weights
// respilled (VGPR stuck at 88 across 4 allocator-fighting rounds — final
// verdict: per-thread weight arrays are unachievable; LDS cannot spill).
// This round combines them:
//   - weights in LDS, lane=channel: ds_read_b128 contiguous (conflict-free),
//     only 16 reads/wave/step -> LDS pipe ~1536 cyc/block/step.
//   - tau broadcast via v_readlane of the polled registers (VALU, 4 SIMDs)
//     instead of LDS broadcast reads -> big shared-pipe relief vs r8.
//   - ALL waves poll xchg (self included; self's L2 trip parallels partners').
//   - part[] parity double-buffer -> ONE barrier per step (ordering of
//     part reuse is transitive through the publish/poll chain).
//   - publish-early epilogue: xchg store issued straight after tau; the
//     v/spike/AmOut tail runs off the inter-block critical path.
// FMA accumulation order and 8-slot reduce are bit-identical to r9 (passed).
// ---------------------------------------------------------------------------
__global__ __launch_bounds__(512)
__attribute__((amdgpu_waves_per_eu(2, 2)))
void scan_rl(const float* __restrict__ WTh,
             const float* __restrict__ Mm,
             const float* __restrict__ log_thresh,
             float* __restrict__ AmOut,   // A in / spikes out (d_out)
             float* __restrict__ OutTail, // d_out base for tau/v tails
             u64* __restrict__ xchg,
             int* __restrict__ ctr) {
    __shared__ __align__(16) float4 w_lds[8192];       // 128 KB
    __shared__ __align__(16) float part[2][2][8][64];  // 16 KB [par][b][slot][ch]
    __shared__ int role_s;

    const int tid = threadIdx.x;

    if (tid == 0) {
        unsigned xcd;
        asm volatile("s_getreg_b32 %0, hwreg(HW_REG_XCC_ID)" : "=s"(xcd));
        xcd &= 7;
        int rank = atomicAdd(&ctr[xcd], 1) & 31;
        role_s = ((rank & 7) << 8) | ((int)xcd * 4 + (rank >> 3));
    }
    __syncthreads();
    const int sg = role_s >> 8;    // channel segment 0..7
    const int bp = role_s & 255;   // batch pair 0..31

    // ---- stage weight slice into LDS (one-time, 128 KB) ----
    // layout: float4 (kq, ch) = {W[4kq..4kq+3][sg*64+ch]}
    {
        const int ch = tid & 63;
        const int kr8 = tid >> 6;          // 0..7
        float* wl = (float*)w_lds;
        for (int i = 0; i < 64; i++) {
            int krow = i * 8 + kr8;
            wl[(krow >> 2) * 256 + ch * 4 + (krow & 3)] =
                WTh[krow * 512 + sg * 64 + ch];
        }
    }

    const int ws = tid >> 6;       // wave = k-window [ws*64,+64) = segment ws
    const int lane = tid & 63;     // lane = channel within the window/output

    // epilogue identity (tid < 128): batch-in-pair eb, channel ech
    const int eb = tid >> 6;             // 0 or 1
    const int ech = tid & 63;
    const int gch = sg * 64 + ech;
    float thr = 0.f, v = 0.f, tau_keep = 0.f;
    if (tid < 128) thr = 1.0f / (1.0f + expf(-log_thresh[gch]));
    size_t abase = ((size_t)(bp * 2 + eb) * T_) * D_ + gch;

    // prime the A/M software pipeline (step 1's values)
    float a_pf = 0.f, m_pf = 0.f;
    if (tid < 128) { a_pf = AmOut[abase]; m_pf = Mm[abase]; }
    __syncthreads();   // weights staged

    for (int c = 1; c <= T_; c++) {
        // issue next step's A/M loads (consumed next iteration's epilogue)
        float a_nx = 0.f, m_nx = 0.f;
        if (tid < 128) {
            size_t nx = (c < T_) ? abase + D_ : abase;
            a_nx = AmOut[nx]; m_nx = Mm[nx];
        }

        // ---- poll own source segment (all waves; 2 words per lane) ----
        const u64* s0 = xchg + (size_t)((c - 1) & 1) * XWORDS
                             + (size_t)(bp * 2) * 512 + ws * 64 + lane;
        const u64* s1 = s0 + 512;   // batch 1 of the pair
        const unsigned tgt = (unsigned)(c - 1);
        u64 v0, v1;
        int guard = 0;
        do {
            v0 = __hip_atomic_load(s0, __ATOMIC_RELAXED,
                                   __HIP_MEMORY_SCOPE_AGENT);
            v1 = __hip_atomic_load(s1, __ATOMIC_RELAXED,
                                   __HIP_MEMORY_SCOPE_AGENT);
        } while ((((unsigned)(v0 >> 32) < tgt) |
                  ((unsigned)(v1 >> 32) < tgt)) && ++guard < (1 << 22));
        const int t0i = (int)(unsigned)v0;   // tau bits, batch 0
        const int t1i = (int)(unsigned)v1;   // tau bits, batch 1

        // ---- FMA over own 64-k window: LDS weights + readlane tau ----
        float acc0 = 0.f, acc1 = 0.f;
#pragma unroll
        for (int q4 = 0; q4 < 16; q4++) {
            float4 wv = w_lds[(ws * 16 + q4) * 64 + lane];
#pragma unroll
            for (int j = 0; j < 4; j++) {
                const int kk = q4 * 4 + j;
                const float wj = (j == 0) ? wv.x : (j == 1) ? wv.y
                               : (j == 2) ? wv.z : wv.w;
                float ta = __uint_as_float(
                    (unsigned)__builtin_amdgcn_readlane(t0i, kk));
                float tb = __uint_as_float(
                    (unsigned)__builtin_amdgcn_readlane(t1i, kk));
                acc0 = fmaf(ta, wj, acc0);
                acc1 = fmaf(tb, wj, acc1);
            }
        }
        const int par = c & 1;
        part[par][0][ws][lane] = acc0;
        part[par][1][ws][lane] = acc1;
        __syncthreads();   // the ONLY barrier: partials of step c ready

        // ---- epilogue on 128 threads; publish FIRST, tail after ----
        if (tid < 128) {
            float sum = 0.f;
#pragma unroll
            for (int j = 0; j < 8; j++) sum += part[par][eb][j][ech];
            float pre = sum + a_pf;
            float tau = 1.0f / (1.0f + expf(-pre));
            u64 pack = ((u64)(unsigned)c << 32) | (u64)__float_as_uint(tau);
            __hip_atomic_store(&xchg[(size_t)(c & 1) * XWORDS
                                     + (bp * 2 + eb) * 512 + gch],
                               pack, __ATOMIC_RELAXED, __HIP_MEMORY_SCOPE_AGENT);
            // off-critical-path tail
            float alpha = expf(-1.0f / (tau + 1e-6f));
            v = alpha * v + (1.0f - alpha) * m_pf;
            float s = (v >= thr) ? 1.0f : 0.0f;
            AmOut[abase] = s;            // overwrite A slot with spike
            v = v * (1.0f - s);
            tau_keep = tau;
            abase += D_;
            a_pf = a_nx; m_pf = m_nx;    // advance the pipeline
        }
        // no second barrier: next step writes part[par^1]; reuse of part[par]
        // (step c+2) is ordered through publish(c) -> partner(c+1) -> poll.
    }

    if (tid < 128) {
        const size_t batch = bp * 2 + eb;
        OutTail[(size_t)BT_ * D_ + batch * D_ + gch] = tau_keep;
        OutTail[(size_t)BT_ * D_ + (size_t)B_ * D_ + batch * D_ + gch] = v;
    }
}

// ---------------------------------------------------------------------------
extern "C" void kernel_launch(void* const* d_in, const int* in_sizes, int n_in,
                              void* d_out, int out_size, void* d_ws, size_t ws_size,
                              hipStream_t stream) {
    (void)in_sizes; (void)n_in; (void)out_size; (void)ws_size;
    const float* x          = (const float*)d_in[0];
    const float* tau_w      = (const float*)d_in[1];
    const float* tau_b      = (const float*)d_in[2];
    const float* mem_w      = (const float*)d_in[3];
    const float* mem_b      = (const float*)d_in[4];
    const float* log_thresh = (const float*)d_in[5];
    float* out = (float*)d_out;

    // workspace layout
    float* Wcat = (float*)d_ws;            // 512*1024 (dead after GEMM)
    float* WTh  = Wcat + 512 * 1024;       // 512*512
    float* Mout = WTh + 512 * 512;         // 131072*512
    // sync state reuses the Wcat region (GEMM finishes before init_sync)
    u64* xchg = (u64*)d_ws;                           // 2*XWORDS*8 = 512 KB
    int* ctr  = (int*)((char*)d_ws + 2 * XWORDS * sizeof(u64));

    float* Aout = out;                     // spikes region doubles as A buffer

    prep_weights<<<2048, 256, 0, stream>>>(tau_w, mem_w, Wcat, WTh);
    gemm_xw<<<dim3(8, 1024), 256, 0, stream>>>(x, Wcat, tau_b, mem_b, Aout, Mout);
    init_sync<<<256, 256, 0, stream>>>(xchg, ctr);

    const float* WThc = WTh;
    const float* Mmc  = Mout;
    const float* ltc  = log_thresh;
    float* outp = out;
    u64* xchgp = xchg;
    int* ctrp = ctr;
    void* args[7] = {(void*)&WThc, (void*)&Mmc, (void*)&ltc,
                     (void*)&Aout, (void*)&outp, (void*)&xchgp, (void*)&ctrp};
    hipLaunchCooperativeKernel((const void*)scan_rl, dim3(256), dim3(512),
                               args, 0, stream);
}

// Round 12
// 5997.687 us; speedup vs baseline: 1.0066x; 1.0066x over previous
//
#include <hip/hip_runtime.h>
#include <math.h>

#define B_ 64
#define T_ 2048
#define D_ 512
#define BT_ (B_ * T_)   // 131072
#define XWORDS (B_ * D_)   // 32768 8-byte words per parity slot: [batch][512]

typedef unsigned long long u64;
typedef float f32x4 __attribute__((ext_vector_type(4)));   // nontemporal-ok

// ---------------------------------------------------------------------------
// Kernel 1: weight prep (transpose to k-major for coalesced GEMM/GEMV reads)
// ---------------------------------------------------------------------------
__global__ void prep_weights(const float* __restrict__ tau_w,
                             const float* __restrict__ mem_w,
                             float* __restrict__ Wcat,
                             float* __restrict__ WTh) {
    int idx = blockIdx.x * 256 + threadIdx.x;   // 0 .. 524287
    {
        int k = idx >> 10, j = idx & 1023;
        float v = (j < 512) ? tau_w[j * 1024 + k] : mem_w[(j - 512) * 512 + k];
        Wcat[idx] = v;
    }
    if (idx < 512 * 512) {
        int k = idx >> 9, d = idx & 511;
        WTh[idx] = tau_w[d * 1024 + 512 + k];
    }
}

// ---------------------------------------------------------------------------
// Kernel 2: f32 GEMM  C[131072][1024] = X[131072][512] @ Wcat[512][1024] + bias
// Outputs stored NON-TEMPORAL (ext-vector f32x4): re-read exactly once by the
// scan — caching 536 MB of them only thrashes L2 (round-10 diagnosis).
// ---------------------------------------------------------------------------
__global__ __launch_bounds__(256, 2)
void gemm_xw(const float* __restrict__ X, const float* __restrict__ Wc,
             const float* __restrict__ tau_b, const float* __restrict__ mem_b,
             float* __restrict__ Aout, float* __restrict__ Mout) {
    __shared__ __align__(16) float As[16][128];  // [k][m]
    __shared__ __align__(16) float Bs[16][128];  // [k][n]
    const int bn = blockIdx.x;          // 0..7
    const int bm = blockIdx.y;          // 0..1023
    const int tid = threadIdx.x;
    const int tm = (tid >> 4) << 3;
    const int tn = (tid & 15) << 3;
    const int m0 = bm * 128, n0 = bn * 128;

    const float4* X4 = (const float4*)X;
    const float4* Wc4 = (const float4*)Wc;

    float acc[8][8];
#pragma unroll
    for (int i = 0; i < 8; i++)
#pragma unroll
        for (int j = 0; j < 8; j++) acc[i][j] = 0.0f;

    const int ar = tid >> 1;              // 0..127 row in tile
    const int ac2 = (tid & 1) * 2;        // float4 col 0 or 2
    const int bkr = tid >> 4;             // 0..15
    const int bc = (tid & 15) * 2;        // float4 col 0..30

    for (int kt = 0; kt < 512; kt += 16) {
        float4 av0 = X4[(m0 + ar) * 128 + (kt >> 2) + ac2];
        float4 av1 = X4[(m0 + ar) * 128 + (kt >> 2) + ac2 + 1];
        float4 bv0 = Wc4[(kt + bkr) * 256 + bn * 32 + bc];
        float4 bv1 = Wc4[(kt + bkr) * 256 + bn * 32 + bc + 1];
        __syncthreads();   // protect previous iteration's reads
        As[ac2 * 4 + 0][ar] = av0.x;
        As[ac2 * 4 + 1][ar] = av0.y;
        As[ac2 * 4 + 2][ar] = av0.z;
        As[ac2 * 4 + 3][ar] = av0.w;
        As[ac2 * 4 + 4][ar] = av1.x;
        As[ac2 * 4 + 5][ar] = av1.y;
        As[ac2 * 4 + 6][ar] = av1.z;
        As[ac2 * 4 + 7][ar] = av1.w;
        *(float4*)&Bs[bkr][bc * 4] = bv0;
        *(float4*)&Bs[bkr][bc * 4 + 4] = bv1;
        __syncthreads();
#pragma unroll
        for (int kk = 0; kk < 16; kk++) {
            float4 a0 = *(const float4*)&As[kk][tm];
            float4 a1 = *(const float4*)&As[kk][tm + 4];
            float4 b0 = *(const float4*)&Bs[kk][tn];
            float4 b1 = *(const float4*)&Bs[kk][tn + 4];
            float av[8] = {a0.x, a0.y, a0.z, a0.w, a1.x, a1.y, a1.z, a1.w};
            float bv[8] = {b0.x, b0.y, b0.z, b0.w, b1.x, b1.y, b1.z, b1.w};
#pragma unroll
            for (int i = 0; i < 8; i++)
#pragma unroll
                for (int j = 0; j < 8; j++)
                    acc[i][j] = fmaf(av[i], bv[j], acc[i][j]);
        }
    }

    const bool isA = (bn < 4);
    float* Cout = isA ? Aout : Mout;
    const float* bias = isA ? tau_b : mem_b;
    const int ncol0 = (isA ? n0 : n0 - 512) + tn;
    float bj[8];
#pragma unroll
    for (int j = 0; j < 8; j++) bj[j] = bias[ncol0 + j];
#pragma unroll
    for (int i = 0; i < 8; i++) {
        size_t off = (size_t)(m0 + tm + i) * 512 + ncol0;
        f32x4 o0, o1;
        o0.x = acc[i][0] + bj[0]; o0.y = acc[i][1] + bj[1];
        o0.z = acc[i][2] + bj[2]; o0.w = acc[i][3] + bj[3];
        o1.x = acc[i][4] + bj[4]; o1.y = acc[i][5] + bj[5];
        o1.z = acc[i][6] + bj[6]; o1.w = acc[i][7] + bj[7];
        __builtin_nontemporal_store(o0, (f32x4*)&Cout[off]);
        __builtin_nontemporal_store(o1, (f32x4*)&Cout[off + 4]);
    }
}

// ---------------------------------------------------------------------------
// Kernel 3: reset sync state every launch (graph-replay safe).
// Slot0 words = {seq=0, tau=1.0} (the t=0 carry); slot1 words = {seq=0, *}.
// ---------------------------------------------------------------------------
__global__ void init_sync(u64* __restrict__ xchg, int* __restrict__ ctr) {
    int idx = blockIdx.x * 256 + threadIdx.x;   // 0 .. 65535
    if (idx < 2 * XWORDS) xchg[idx] = (idx < XWORDS) ? 0x3F800000ull : 0ull;
    if (idx < 16) ctr[idx] = 0;
}

// ---------------------------------------------------------------------------
// Kernel 4: cooperative scan — LDS weights + readlane tau + 1-barrier step
// + NON-TEMPORAL streams.
//
// Round-10 diagnosis: WRITE_SIZE 787MB vs 280 expected = the per-step xchg
// publishes were evicted to HBM by the 536MB A/M streams thrashing L2 ->
// every sync hop ran at HBM latency (~900cy, m126) not L2 (~200-300cy).
// Fix: A/M loads and spike stores are nontemporal (read/written exactly
// once); xchg atomics stay cached. Everything else identical to round 10.
// ---------------------------------------------------------------------------
__global__ __launch_bounds__(512)
__attribute__((amdgpu_waves_per_eu(2, 2)))
void scan_nt(const float* __restrict__ WTh,
             const float* __restrict__ Mm,
             const float* __restrict__ log_thresh,
             float* __restrict__ AmOut,   // A in / spikes out (d_out)
             float* __restrict__ OutTail, // d_out base for tau/v tails
             u64* __restrict__ xchg,
             int* __restrict__ ctr) {
    __shared__ __align__(16) float4 w_lds[8192];       // 128 KB
    __shared__ __align__(16) float part[2][2][8][64];  // 16 KB [par][b][slot][ch]
    __shared__ int role_s;

    const int tid = threadIdx.x;

    if (tid == 0) {
        unsigned xcd;
        asm volatile("s_getreg_b32 %0, hwreg(HW_REG_XCC_ID)" : "=s"(xcd));
        xcd &= 7;
        int rank = atomicAdd(&ctr[xcd], 1) & 31;
        role_s = ((rank & 7) << 8) | ((int)xcd * 4 + (rank >> 3));
    }
    __syncthreads();
    const int sg = role_s >> 8;    // channel segment 0..7
    const int bp = role_s & 255;   // batch pair 0..31

    // ---- stage weight slice into LDS (one-time, 128 KB) ----
    {
        const int ch = tid & 63;
        const int kr8 = tid >> 6;          // 0..7
        float* wl = (float*)w_lds;
        for (int i = 0; i < 64; i++) {
            int krow = i * 8 + kr8;
            wl[(krow >> 2) * 256 + ch * 4 + (krow & 3)] =
                WTh[krow * 512 + sg * 64 + ch];
        }
    }

    const int ws = tid >> 6;       // wave = k-window [ws*64,+64) = segment ws
    const int lane = tid & 63;     // lane = channel within the window/output

    // epilogue identity (tid < 128): batch-in-pair eb, channel ech
    const int eb = tid >> 6;             // 0 or 1
    const int ech = tid & 63;
    const int gch = sg * 64 + ech;
    float thr = 0.f, v = 0.f, tau_keep = 0.f;
    if (tid < 128) thr = 1.0f / (1.0f + expf(-log_thresh[gch]));
    size_t abase = ((size_t)(bp * 2 + eb) * T_) * D_ + gch;

    // prime the A/M software pipeline (step 1's values) — nontemporal
    float a_pf = 0.f, m_pf = 0.f;
    if (tid < 128) {
        a_pf = __builtin_nontemporal_load(&AmOut[abase]);
        m_pf = __builtin_nontemporal_load(&Mm[abase]);
    }
    __syncthreads();   // weights staged

    for (int c = 1; c <= T_; c++) {
        // issue next step's A/M loads (consumed next iteration's epilogue)
        float a_nx = 0.f, m_nx = 0.f;
        if (tid < 128) {
            size_t nx = (c < T_) ? abase + D_ : abase;
            a_nx = __builtin_nontemporal_load(&AmOut[nx]);
            m_nx = __builtin_nontemporal_load(&Mm[nx]);
        }

        // ---- poll own source segment (all waves; 2 words per lane) ----
        const u64* s0 = xchg + (size_t)((c - 1) & 1) * XWORDS
                             + (size_t)(bp * 2) * 512 + ws * 64 + lane;
        const u64* s1 = s0 + 512;   // batch 1 of the pair
        const unsigned tgt = (unsigned)(c - 1);
        u64 v0, v1;
        int guard = 0;
        do {
            v0 = __hip_atomic_load(s0, __ATOMIC_RELAXED,
                                   __HIP_MEMORY_SCOPE_AGENT);
            v1 = __hip_atomic_load(s1, __ATOMIC_RELAXED,
                                   __HIP_MEMORY_SCOPE_AGENT);
        } while ((((unsigned)(v0 >> 32) < tgt) |
                  ((unsigned)(v1 >> 32) < tgt)) && ++guard < (1 << 22));
        const int t0i = (int)(unsigned)v0;   // tau bits, batch 0
        const int t1i = (int)(unsigned)v1;   // tau bits, batch 1

        // ---- FMA over own 64-k window: LDS weights + readlane tau ----
        float acc0 = 0.f, acc1 = 0.f;
#pragma unroll
        for (int q4 = 0; q4 < 16; q4++) {
            float4 wv = w_lds[(ws * 16 + q4) * 64 + lane];
#pragma unroll
            for (int j = 0; j < 4; j++) {
                const int kk = q4 * 4 + j;
                const float wj = (j == 0) ? wv.x : (j == 1) ? wv.y
                               : (j == 2) ? wv.z : wv.w;
                float ta = __uint_as_float(
                    (unsigned)__builtin_amdgcn_readlane(t0i, kk));
                float tb = __uint_as_float(
                    (unsigned)__builtin_amdgcn_readlane(t1i, kk));
                acc0 = fmaf(ta, wj, acc0);
                acc1 = fmaf(tb, wj, acc1);
            }
        }
        const int par = c & 1;
        part[par][0][ws][lane] = acc0;
        part[par][1][ws][lane] = acc1;
        __syncthreads();   // the ONLY barrier: partials of step c ready

        // ---- epilogue on 128 threads; publish FIRST, tail after ----
        if (tid < 128) {
            float sum = 0.f;
#pragma unroll
            for (int j = 0; j < 8; j++) sum += part[par][eb][j][ech];
            float pre = sum + a_pf;
            float tau = 1.0f / (1.0f + expf(-pre));
            u64 pack = ((u64)(unsigned)c << 32) | (u64)__float_as_uint(tau);
            __hip_atomic_store(&xchg[(size_t)(c & 1) * XWORDS
                                     + (bp * 2 + eb) * 512 + gch],
                               pack, __ATOMIC_RELAXED, __HIP_MEMORY_SCOPE_AGENT);
            // off-critical-path tail
            float alpha = expf(-1.0f / (tau + 1e-6f));
            v = alpha * v + (1.0f - alpha) * m_pf;
            float s = (v >= thr) ? 1.0f : 0.0f;
            __builtin_nontemporal_store(s, &AmOut[abase]);  // spike out
            v = v * (1.0f - s);
            tau_keep = tau;
            abase += D_;
            a_pf = a_nx; m_pf = m_nx;    // advance the pipeline
        }
        // no second barrier: next step writes part[par^1]; reuse of part[par]
        // (step c+2) is ordered through publish(c) -> partner(c+1) -> poll.
    }

    if (tid < 128) {
        const size_t batch = bp * 2 + eb;
        OutTail[(size_t)BT_ * D_ + batch * D_ + gch] = tau_keep;
        OutTail[(size_t)BT_ * D_ + (size_t)B_ * D_ + batch * D_ + gch] = v;
    }
}

// ---------------------------------------------------------------------------
extern "C" void kernel_launch(void* const* d_in, const int* in_sizes, int n_in,
                              void* d_out, int out_size, void* d_ws, size_t ws_size,
                              hipStream_t stream) {
    (void)in_sizes; (void)n_in; (void)out_size; (void)ws_size;
    const float* x          = (const float*)d_in[0];
    const float* tau_w      = (const float*)d_in[1];
    const float* tau_b      = (const float*)d_in[2];
    const float* mem_w      = (const float*)d_in[3];
    const float* mem_b      = (const float*)d_in[4];
    const float* log_thresh = (const float*)d_in[5];
    float* out = (float*)d_out;

    // workspace layout
    float* Wcat = (float*)d_ws;            // 512*1024 (dead after GEMM)
    float* WTh  = Wcat + 512 * 1024;       // 512*512
    float* Mout = WTh + 512 * 512;         // 131072*512
    // sync state reuses the Wcat region (GEMM finishes before init_sync)
    u64* xchg = (u64*)d_ws;                           // 2*XWORDS*8 = 512 KB
    int* ctr  = (int*)((char*)d_ws + 2 * XWORDS * sizeof(u64));

    float* Aout = out;                     // spikes region doubles as A buffer

    prep_weights<<<2048, 256, 0, stream>>>(tau_w, mem_w, Wcat, WTh);
    gemm_xw<<<dim3(8, 1024), 256, 0, stream>>>(x, Wcat, tau_b, mem_b, Aout, Mout);
    init_sync<<<256, 256, 0, stream>>>(xchg, ctr);

    const float* WThc = WTh;
    const float* Mmc  = Mout;
    const float* ltc  = log_thresh;
    float* outp = out;
    u64* xchgp = xchg;
    int* ctrp = ctr;
    void* args[7] = {(void*)&WThc, (void*)&Mmc, (void*)&ltc,
                     (void*)&Aout, (void*)&outp, (void*)&xchgp, (void*)&ctrp};
    hipLaunchCooperativeKernel((const void*)scan_nt, dim3(256), dim3(512),
                               args, 0, stream);
}